// Round 12
// baseline (403.052 us; speedup 1.0000x reference)
//
#include <hip/hip_runtime.h>
#include <hip/hip_fp16.h>
#include <hip/hip_fp8.h>

#define B_ 256
#define V_ 1000
#define P_ 200
#define L_ 50
#define H_ 384
#define H3_ 1152
#define NW_ 10
#define OUT1_OFF 12800000

typedef _Float16 half8 __attribute__((ext_vector_type(8)));
typedef _Float16 half4_t __attribute__((ext_vector_type(4)));
typedef _Float16 half2_t __attribute__((ext_vector_type(2)));
typedef float floatx4 __attribute__((ext_vector_type(4)));

// ---------------------------------------------------------------------------
// prep: fp8 pair-packed w_hh, 4-wave layout (wave owns 96 cols/gate):
//   whhR (reg-persist, j=0..3): byte i = ((w*72 + u)*64 + l)*16 + p*8 + e
//       u in [0,72): j=u/18, rem=u%18, g=rem/6, kap=rem%6
//   whhP (LDS-persist, j=4..5): byte i = ((w*36 + v)*64 + l)*16 + p*8 + e
//       v in [0,36): j=4+v/18, rem=v%18, g=rem/6, kap=rem%6
// Common: kc=2*kap+p; row = g*384 + 96w + 16j + (l&15);
//         col = kc*32 + (l>>4)*8 + e
// ---------------------------------------------------------------------------
__global__ __launch_bounds__(256) void prep_kernel(
    const float* __restrict__ gate_emb, const float* __restrict__ prog_emb,
    const float* __restrict__ w_ih, const float* __restrict__ w_hh,
    const int* __restrict__ instr, const int* __restrict__ tacts,
    float* __restrict__ g01, unsigned char* __restrict__ whhP,
    unsigned char* __restrict__ whhR,
    _Float16* __restrict__ wih_h, _Float16* __restrict__ prog_h,
    float* __restrict__ out)
{
  const int stride = gridDim.x * blockDim.x;
  const int tid = blockIdx.x * blockDim.x + threadIdx.x;

  for (int i = tid; i < 147456; i += stride) {
    const int e = i & 7, p = (i >> 3) & 1, l = (i >> 4) & 63;
    const int q = i >> 10;                 // [0,144) = w*36 + v
    const int v = q % 36, w = q / 36;
    const int j = 4 + v / 18, rem = v % 18;
    const int g = rem / 6, kap = rem - 6*g;
    const int kc = 2*kap + p;
    const int row = g*384 + 96*w + 16*j + (l & 15);
    const int col = kc*32 + (l >> 4)*8 + e;
    __hip_fp8_e4m3 qv(w_hh[row*H_ + col]);
    whhP[i] = qv.__x;
  }
  for (int i = tid; i < 294912; i += stride) {
    const int e = i & 7, p = (i >> 3) & 1, l = (i >> 4) & 63;
    const int q = i >> 10;                 // [0,288) = w*72 + u
    const int u = q % 72, w = q / 72;
    const int j = u / 18, rem = u % 18;
    const int g = rem / 6, kap = rem - 6*g;
    const int kc = 2*kap + p;
    const int row = g*384 + 96*w + 16*j + (l & 15);
    const int col = kc*32 + (l >> 4)*8 + e;
    __hip_fp8_e4m3 qv(w_hh[row*H_ + col]);
    whhR[i] = qv.__x;
  }
  for (int i = tid; i < H3_*224; i += stride) {
    int r = i / 224, c = i - r*224;
    wih_h[i] = (_Float16)(c < P_ ? w_ih[r*P_ + c] : 0.f);
  }
  for (int i = tid; i < V_*P_; i += stride) prog_h[i] = (_Float16)prog_emb[i];
  for (int i = tid; i < NW_*B_; i += stride) {
    int w = i / B_, b = i - w*B_;
    int word = instr[(1+w)*B_ + b];
    float e0 = gate_emb[word*2], e1 = gate_emb[word*2+1];
    float m = fmaxf(e0, e1);
    float a = __expf(e0-m), c = __expf(e1-m);
    float inv = 1.f/(a+c);
    g01[i*2] = a*inv; g01[i*2+1] = c*inv;
  }
  for (int i = tid; i < B_*L_; i += stride) {
    int b = i / L_, l = i - b*L_;
    out[OUT1_OFF + i] = (float)tacts[(1+l)*B_ + b];
  }
}

// ---------------------------------------------------------------------------
// gi_gemm: giv[v][n] = program_emb[v] @ w_ih.T + b_ih (+ b_hh for r/z gates)
// ---------------------------------------------------------------------------
__global__ __launch_bounds__(256) void gi_gemm(
    const _Float16* __restrict__ prog_h, const _Float16* __restrict__ wih_h,
    const float* __restrict__ b_ih, const float* __restrict__ b_hh,
    float* __restrict__ giv)
{
  __shared__ _Float16 pA[16][232];
  const int tid = threadIdx.x;
  const int v0 = blockIdx.x * 16;
  const int n0 = blockIdx.y * 64;

  for (int i = tid; i < 16*224; i += 256) {
    int r = i / 224, c = i - r*224;
    int v = v0 + r;
    _Float16 val = (_Float16)0.f;
    if (v < V_ && c < P_) val = prog_h[v*P_ + c];
    pA[r][c] = val;
  }
  __syncthreads();

  const int wave = tid >> 6, lane = tid & 63;
  const int m = lane & 15, kg = lane >> 4;
  const int n_t = n0 + wave*16;
  floatx4 acc = {0.f, 0.f, 0.f, 0.f};
  #pragma unroll
  for (int ks = 0; ks < 7; ++ks) {
    const int kk = ks*32 + kg*8;
    half8 av = *(const half8*)&pA[m][kk];
    half8 bv = *(const half8*)&wih_h[(n_t + m)*224 + kk];
    acc = __builtin_amdgcn_mfma_f32_16x16x32_f16(av, bv, acc, 0, 0, 0);
  }
  const int nn = n_t + m;
  const float bias = b_ih[nn] + (nn < 768 ? b_hh[nn] : 0.f);
  #pragma unroll
  for (int r = 0; r < 4; ++r) {
    int mm = v0 + kg*4 + r;
    if (mm < V_) giv[(size_t)mm*H3_ + nn] = acc[r] + bias;
  }
}

// ---------------------------------------------------------------------------
// steps: GRU recurrence, 16 blocks x 256 threads (4 waves, 1 wave/SIMD,
// 512-VGPR budget via amdgpu_waves_per_eu(1,1)). ENTIRE w_hh on-CU:
// 72 units/wave as 144 named u64 registers (288 VGPRs) + 36 units/wave in
// LDS (144 KB). Zero VMEM loads in the steady loop. 2 raw lgkm barriers/step.
// ---------------------------------------------------------------------------
__global__ __launch_bounds__(256)
__attribute__((amdgpu_waves_per_eu(1, 1)))
void steps_kernel(
    const uint4* __restrict__ whhPp, const uint4* __restrict__ whhRp,
    const float* __restrict__ giv, const float* __restrict__ g01,
    const float* __restrict__ keys, const float* __restrict__ bhh,
    const int* __restrict__ instr, _Float16* __restrict__ hdump)
{
  __shared__ uint4 ldsP[9216];             // 147456 B persistent weights (j=4,5)
  __shared__ unsigned long long hA[768];   // 6144 B fp8 h image

  const int bid = blockIdx.x, b0 = bid*16, tid = threadIdx.x;
  const int w = tid >> 6, lane = tid & 63, m_ = lane & 15, kg = lane >> 4;

  for (int i = tid; i < 9216; i += 256) ldsP[i] = whhPp[i];

  const uint4* __restrict__ rbase = whhRp + (size_t)w*72*64 + lane;

  float hreg[6][4];        // [j][r]: col 96w+16j+m_, batch kg*4+r
  float bbn[6];            // n-gate b_hh per j
  half2_t gvh[36];         // gi values f16 pairs, flat f = (r*6+j)*3+g
  float g0r[4], g1r[4];

  #pragma unroll
  for (int j = 0; j < 6; ++j) bbn[j] = bhh[768 + 96*w + 16*j + m_];

  // h0 = tile(scratch_keys[0], 3)
  #pragma unroll
  for (int j = 0; j < 6; ++j) {
    const float h0 = keys[(96*w + 16*j + m_) & 127];
    #pragma unroll
    for (int r = 0; r < 4; ++r) hreg[j][r] = h0;
  }

  // initial fp8 hA image + h dump slot 0
  #pragma unroll
  for (int j = 0; j < 6; ++j) {
    const int c = 96*w + 16*j + m_;
    const int base = (c >> 5)*512 + ((c >> 3) & 3)*128 + (c & 7);
    half4_t hv;
    #pragma unroll
    for (int r = 0; r < 4; ++r) {
      __hip_fp8_e4m3 q(hreg[j][r]);
      ((unsigned char*)hA)[base + (kg*4 + r)*8] = q.__x;
      hv[r] = (_Float16)hreg[j][r];
    }
    *(half4_t*)&hdump[(((size_t)0*16 + bid)*384 + c)*16 + kg*4] = hv;
  }

#define LOADGI(WI) { \
    int4 wd4_ = *(const int4*)&instr[(1+(WI))*B_ + b0 + kg*4]; \
    int wdr_[4] = {wd4_.x, wd4_.y, wd4_.z, wd4_.w}; \
    _Pragma("unroll") \
    for (int r = 0; r < 4; ++r) { \
      float2 gg_ = *(const float2*)&g01[((size_t)(WI)*B_ + b0 + kg*4 + r)*2]; \
      g0r[r] = gg_.x; g1r[r] = gg_.y; \
    } \
    _Pragma("unroll") \
    for (int r = 0; r < 4; ++r) { \
      const float* gp_ = giv + (size_t)wdr_[r]*H3_; \
      _Pragma("unroll") \
      for (int j = 0; j < 6; ++j) \
        _Pragma("unroll") \
        for (int g = 0; g < 3; ++g) { \
          const int f_ = (r*6 + j)*3 + g; \
          gvh[f_ >> 1][f_ & 1] = (_Float16)gp_[g*384 + 96*w + 16*j + m_]; \
        } \
    } }

  LOADGI(0)

  // ---- 72 weight units in NAMED u64 registers (288 VGPRs), loaded ONCE ----
#define DECLU(NAME, IDX) \
  unsigned long long NAME##L, NAME##H; \
  { uint4 t_ = rbase[(IDX)*64]; \
    NAME##L = (((unsigned long long)t_.y) << 32) | t_.x; \
    NAME##H = (((unsigned long long)t_.w) << 32) | t_.z; }
#define DECLJ(J) \
  DECLU(W##J##g0k0, (J)*18+ 0) DECLU(W##J##g0k1, (J)*18+ 1) DECLU(W##J##g0k2, (J)*18+ 2) \
  DECLU(W##J##g0k3, (J)*18+ 3) DECLU(W##J##g0k4, (J)*18+ 4) DECLU(W##J##g0k5, (J)*18+ 5) \
  DECLU(W##J##g1k0, (J)*18+ 6) DECLU(W##J##g1k1, (J)*18+ 7) DECLU(W##J##g1k2, (J)*18+ 8) \
  DECLU(W##J##g1k3, (J)*18+ 9) DECLU(W##J##g1k4, (J)*18+10) DECLU(W##J##g1k5, (J)*18+11) \
  DECLU(W##J##g2k0, (J)*18+12) DECLU(W##J##g2k1, (J)*18+13) DECLU(W##J##g2k2, (J)*18+14) \
  DECLU(W##J##g2k3, (J)*18+15) DECLU(W##J##g2k4, (J)*18+16) DECLU(W##J##g2k5, (J)*18+17)

  DECLJ(0) DECLJ(1) DECLJ(2) DECLJ(3)

#define PINU(NAME) asm volatile("" : "+v"(NAME##L), "+v"(NAME##H));
#define PINJ(J) \
  PINU(W##J##g0k0) PINU(W##J##g0k1) PINU(W##J##g0k2) PINU(W##J##g0k3) PINU(W##J##g0k4) PINU(W##J##g0k5) \
  PINU(W##J##g1k0) PINU(W##J##g1k1) PINU(W##J##g1k2) PINU(W##J##g1k3) PINU(W##J##g1k4) PINU(W##J##g1k5) \
  PINU(W##J##g2k0) PINU(W##J##g2k1) PINU(W##J##g2k2) PINU(W##J##g2k3) PINU(W##J##g2k4) PINU(W##J##g2k5)

  PINJ(0) PINJ(1) PINJ(2) PINJ(3)

  asm volatile("s_waitcnt lgkmcnt(0)\n\ts_barrier" ::: "memory");  // hA+ldsP ready

#define MFMA_(ACC, A, B) \
  ACC = __builtin_amdgcn_mfma_f32_16x16x32_fp8_fp8((long)(A), (long)(B), ACC, 0, 0, 0)
#define Z4 ((floatx4){0.f, 0.f, 0.f, 0.f})
#define GVF(F) ((float)gvh[(F) >> 1][(F) & 1])
#define KAP6(K, R, Zw, N) \
  MFMA_(acc0, av[2*(K)],   R##L); \
  MFMA_(acc1, av[2*(K)],   Zw##L); \
  MFMA_(acc2, av[2*(K)],   N##L); \
  MFMA_(acc0, av[2*(K)+1], R##H); \
  MFMA_(acc1, av[2*(K)+1], Zw##H); \
  MFMA_(acc2, av[2*(K)+1], N##H);
#define KAPL(J, K) { \
  uint4 P0 = ldsP[(w*36 + ((J)-4)*18 +      (K))*64 + lane]; \
  uint4 P1 = ldsP[(w*36 + ((J)-4)*18 +  6 + (K))*64 + lane]; \
  uint4 P2 = ldsP[(w*36 + ((J)-4)*18 + 12 + (K))*64 + lane]; \
  MFMA_(acc0, av[2*(K)],   (((unsigned long long)P0.y) << 32) | P0.x); \
  MFMA_(acc1, av[2*(K)],   (((unsigned long long)P1.y) << 32) | P1.x); \
  MFMA_(acc2, av[2*(K)],   (((unsigned long long)P2.y) << 32) | P2.x); \
  MFMA_(acc0, av[2*(K)+1], (((unsigned long long)P0.w) << 32) | P0.z); \
  MFMA_(acc1, av[2*(K)+1], (((unsigned long long)P1.w) << 32) | P1.z); \
  MFMA_(acc2, av[2*(K)+1], (((unsigned long long)P2.w) << 32) | P2.z); }
#define EPI(J) \
  _Pragma("unroll") \
  for (int r = 0; r < 4; ++r) { \
    const float rg = 1.f/(1.f + __expf(-(GVF((r*6+(J))*3+0) + acc0[r]))); \
    const float z  = 1.f/(1.f + __expf(-(GVF((r*6+(J))*3+1) + acc1[r]))); \
    const float x2 = GVF((r*6+(J))*3+2) + rg*(acc2[r] + bbn[(J)]); \
    const float nn = 2.f/(1.f + __expf(-2.f*x2)) - 1.f; \
    const float hold = hreg[(J)][r]; \
    const float hnew = (1.f - z)*nn + z*hold; \
    hreg[(J)][r] = g0r[r]*hold + g1r[r]*hnew; \
  }
#define JREG(J) \
  acc0 = Z4; acc1 = Z4; acc2 = Z4; \
  KAP6(0, W##J##g0k0, W##J##g1k0, W##J##g2k0) \
  KAP6(1, W##J##g0k1, W##J##g1k1, W##J##g2k1) \
  KAP6(2, W##J##g0k2, W##J##g1k2, W##J##g2k2) \
  KAP6(3, W##J##g0k3, W##J##g1k3, W##J##g2k3) \
  KAP6(4, W##J##g0k4, W##J##g1k4, W##J##g2k4) \
  KAP6(5, W##J##g0k5, W##J##g1k5, W##J##g2k5) \
  EPI(J)
#define JLDS(J) \
  acc0 = Z4; acc1 = Z4; acc2 = Z4; \
  KAPL(J, 0) KAPL(J, 1) KAPL(J, 2) KAPL(J, 3) KAPL(J, 4) KAPL(J, 5) \
  EPI(J)

  #pragma unroll 1
  for (int t = 0; t < 30; ++t) {
    unsigned long long av[12];
    #pragma unroll
    for (int kc = 0; kc < 12; ++kc) av[kc] = hA[kc*64 + lane];
    asm volatile("s_waitcnt lgkmcnt(0)\n\ts_barrier" ::: "memory"); // reads done

    floatx4 acc0, acc1, acc2;
    JREG(0) JREG(1) JREG(2) JREG(3) JLDS(4) JLDS(5)

    // ---- new fp8 hA image + h dump slot t+1 ----
    #pragma unroll
    for (int j = 0; j < 6; ++j) {
      const int c = 96*w + 16*j + m_;
      const int base = (c >> 5)*512 + ((c >> 3) & 3)*128 + (c & 7);
      half4_t hv;
      #pragma unroll
      for (int r = 0; r < 4; ++r) {
        __hip_fp8_e4m3 q(hreg[j][r]);
        ((unsigned char*)hA)[base + (kg*4 + r)*8] = q.__x;
        hv[r] = (_Float16)hreg[j][r];
      }
      *(half4_t*)&hdump[(((size_t)(t+1)*16 + bid)*384 + c)*16 + kg*4] = hv;
    }

    if (t % 3 == 2) {
      const int wi = (t/3 + 1 < 10) ? t/3 + 1 : 9;
      LOADGI(wi)
    }

    asm volatile("s_waitcnt lgkmcnt(0)\n\ts_barrier" ::: "memory"); // hA writes
  }
  asm volatile("s_waitcnt vmcnt(0) lgkmcnt(0)" ::: "memory");
#undef JREG
#undef JLDS
#undef KAP6
#undef KAPL
#undef EPI
#undef GVF
#undef Z4
#undef MFMA_
#undef PINJ
#undef PINU
#undef DECLJ
#undef DECLU
#undef LOADGI
}

// ---------------------------------------------------------------------------
// attnS: decoupled attention/S recurrence, one block per batch element.
// ---------------------------------------------------------------------------
__global__ __launch_bounds__(256) void attnS_kernel(
    const _Float16* __restrict__ hdump, const float* __restrict__ keys,
    const float* __restrict__ g01, float* __restrict__ S_buf)
{
  __shared__ float keysT[128][52];   // [k][l]
  __shared__ float hT[30][256];      // h cols 128..383 per step
  __shared__ float sc[30][2][52];    // softmax probs
  __shared__ float Sr[50][13];
  __shared__ float g0a[10], g1a[10];
  __shared__ float nvs[12];

  const int b = blockIdx.x, g = b >> 4, bl = b & 15;
  const int tid = threadIdx.x, wv = tid >> 6, lane = tid & 63;

  for (int i = tid; i < 128*L_; i += 256) {
    int k = i / L_, l = i - k*L_;
    keysT[k][l] = keys[l*128 + k];
  }
  for (int i = tid; i < 30*256; i += 256) {
    int t = i >> 8, c = i & 255;
    hT[t][c] = (float)hdump[(((size_t)t*16 + g)*384 + 128 + c)*16 + bl];
  }
  for (int i = tid; i < 550; i += 256) Sr[i/11][i%11] = ((i % 11) == 0) ? 1.f : 0.f;
  if (tid < NW_) {
    float2 gg = *(const float2*)&g01[((size_t)tid*B_ + b)*2];
    g0a[tid] = gg.x; g1a[tid] = gg.y;
  }
  __syncthreads();

  // ---- phase 1: 60 score rows, 15 per wave ----
  for (int row = wv; row < 60; row += 4) {
    const int t = row >> 1, ty = row & 1;
    float s = 0.f;
    if (lane < L_) {
      #pragma unroll 8
      for (int k = 0; k < 128; ++k)
        s += hT[t][ty*128 + k] * keysT[k][lane];
    }
    float val = (lane < L_) ? s : -1e30f;
    float mx = val;
    #pragma unroll
    for (int off = 32; off; off >>= 1) mx = fmaxf(mx, __shfl_xor(mx, off));
    float e = (lane < L_) ? __expf(val - mx) : 0.f;
    float sm = e;
    #pragma unroll
    for (int off = 32; off; off >>= 1) sm += __shfl_xor(sm, off);
    if (lane < L_) sc[t][ty][lane] = e / sm;
  }
  __syncthreads();

  // ---- phase 2: S recurrence ----
  for (int t = 0; t < 30; ++t) {
    const int widx = t / 3;
    if (tid < 11) {
      float rv = 0.f;
      #pragma unroll 5
      for (int l = 0; l < L_; ++l) rv += sc[t][0][l] * Sr[l][tid];
      nvs[tid] = g1a[widx]*rv + ((tid == 1 + widx) ? g0a[widx] : 0.f);
    }
    __syncthreads();
    for (int i = tid; i < 550; i += 256) {
      const int l = i / 11, j = i - l*11;
      const float wm = sc[t][1][l];
      Sr[l][j] = wm*nvs[j] + (1.f - wm)*Sr[l][j];
    }
    __syncthreads();
  }

  for (int i = tid; i < 550; i += 256) {
    const int l = i / 11, j = i - l*11;
    S_buf[(size_t)b*600 + l*12 + j] = Sr[l][j];
  }
}

// ---------------------------------------------------------------------------
// epi: merged lse + write, ONE block per batch element.
// ---------------------------------------------------------------------------
__global__ __launch_bounds__(512) void epi_kernel(
    const float* __restrict__ S_buf, const float* __restrict__ prim_emb,
    const float* __restrict__ iv_g, const int* __restrict__ instr,
    float* __restrict__ out)
{
  __shared__ float prim[10][1000];
  __shared__ float iv[1000];
  __shared__ float SrT[11][52];
  __shared__ float lss[52];
  __shared__ int wds[10];

  const int b = blockIdx.x;
  const int tid = threadIdx.x;

  if (tid < 10) wds[tid] = instr[(1+tid)*B_ + b];
  for (int i = tid; i < 550; i += 512) {
    int l = i / 11, j = i - l*11;
    SrT[j][l] = S_buf[(size_t)b*600 + l*12 + j];
  }
  for (int i = tid; i < 250; i += 512) ((float4*)iv)[i] = ((const float4*)iv_g)[i];
  __syncthreads();
  for (int wi = 0; wi < 10; ++wi) {
    const float4* __restrict__ src = (const float4*)(prim_emb + (size_t)wds[wi]*V_);
    for (int i = tid; i < 250; i += 512) ((float4*)prim[wi])[i] = src[i];
  }
  __syncthreads();

  const int wv = tid >> 6, lane = tid & 63;
  for (int l = wv; l < L_; l += 8) {
    float c0 = SrT[0][l];
    float cw[10];
    #pragma unroll
    for (int wi = 0; wi < 10; ++wi) cw[wi] = SrT[1+wi][l];
    float sv[16];
    float mx = -1e30f;
    #pragma unroll
    for (int jj = 0; jj < 16; ++jj) {
      int v = lane + 64*jj;
      float s = -1e30f;
      if (v < V_) {
        s = c0 * iv[v];
        #pragma unroll
        for (int wi = 0; wi < 10; ++wi) s += cw[wi]*prim[wi][v];
      }
      sv[jj] = s;
      mx = fmaxf(mx, s);
    }
    #pragma unroll
    for (int off = 32; off; off >>= 1) mx = fmaxf(mx, __shfl_xor(mx, off));
    float se = 0.f;
    #pragma unroll
    for (int jj = 0; jj < 16; ++jj) {
      int v = lane + 64*jj;
      if (v < V_) se += __expf(sv[jj] - mx);
    }
    #pragma unroll
    for (int off = 32; off; off >>= 1) se += __shfl_xor(se, off);
    if (lane == 0) lss[l] = mx + __logf(se);
  }
  __syncthreads();

  float* __restrict__ dst = out + (size_t)b*50000;
  for (int e = tid; e < 50000; e += 512) {
    const int v = e / 50, l = e - v*50;
    float s = SrT[0][l]*iv[v];
    #pragma unroll
    for (int wi = 0; wi < 10; ++wi) s += SrT[1+wi][l]*prim[wi][v];
    dst[e] = s - lss[l];
  }
}

// ---------------------------------------------------------------------------
extern "C" void kernel_launch(void* const* d_in, const int* in_sizes, int n_in,
                              void* d_out, int out_size, void* d_ws, size_t ws_size,
                              hipStream_t stream)
{
  (void)in_sizes; (void)n_in; (void)out_size; (void)ws_size;
  const float* gate_emb = (const float*)d_in[0];
  const float* prog_emb = (const float*)d_in[1];
  const float* prim_emb = (const float*)d_in[2];
  const float* sk       = (const float*)d_in[3];
  const float* iv       = (const float*)d_in[4];
  const float* w_ih     = (const float*)d_in[5];
  const float* w_hh     = (const float*)d_in[6];
  const float* b_ih     = (const float*)d_in[7];
  const float* b_hh     = (const float*)d_in[8];
  const int*   instr    = (const int*)d_in[9];
  const int*   tacts    = (const int*)d_in[10];
  float* out = (float*)d_out;

  float* ws     = (float*)d_ws;
  float* S_buf  = ws;                          // 256*600 f32
  float* g01    = S_buf + B_*600;              // 5120 f32
  float* giv    = g01 + NW_*B_*2;              // 1,152,000 f32
  unsigned char* whhP = (unsigned char*)(giv + (size_t)V_*H3_);  // 147456 B
  unsigned char* whhR = whhP + 147456;                           // 294912 B
  _Float16* wih_h  = (_Float16*)(whhR + 294912);             // 1152*224 f16
  _Float16* prog_h = wih_h + (size_t)H3_*224;                // 200000 f16
  _Float16* hdump  = prog_h + (size_t)V_*P_;                 // 31*16*384*16 f16

  hipLaunchKernelGGL(prep_kernel, dim3(1024), dim3(256), 0, stream,
      gate_emb, prog_emb, w_ih, w_hh, instr, tacts,
      g01, whhP, whhR, wih_h, prog_h, out);

  hipLaunchKernelGGL(gi_gemm, dim3(63, 18), dim3(256), 0, stream,
      prog_h, wih_h, b_ih, b_hh, giv);

  hipLaunchKernelGGL(steps_kernel, dim3(16), dim3(256), 0, stream,
      (const uint4*)whhP, (const uint4*)whhR, giv, g01, sk, b_hh, instr, hdump);

  hipLaunchKernelGGL(attnS_kernel, dim3(256), dim3(256), 0, stream,
      hdump, sk, g01, S_buf);

  hipLaunchKernelGGL(epi_kernel, dim3(256), dim3(512), 0, stream,
      S_buf, prim_emb, iv, instr, out);
}